// Round 3
// baseline (22.167 us; speedup 1.0000x reference)
//
#include <hip/hip_runtime.h>

#define TOTAL 286
#define KG 32      // grid points per Euler angle
#define LB 6       // bandwidth
#define NM 11      // 2L-1
#define CIN 16
#define COUT 32
#define BB 8
#define NPH 4      // phases per block
#define QPP 8      // q per phase (one per wave)
#define ZROW 12    // padded n-columns (16B-aligned rows)
#define ZPERQ (6 * NM * ZROW)   // 792 floats per (q, channel)

typedef float    v4f __attribute__((ext_vector_type(4)));
typedef _Float16 v4h __attribute__((ext_vector_type(4)));

// One block per (b,o): 256 blocks, 512 threads (8 waves). 4 phases x 8 q = 32 q.
// Per q: S (11x11) -> MFMA T=S*G (16x16x16 f16) -> MFMA resp=ca1'T1+ca2'T2,
// with T chained GEMM->GEMM in registers (D-frag layout == B-frag layout).
__global__ __launch_bounds__(512, 2) void so3_mfma_kernel(
    const float* __restrict__ x,    // [B, CIN, TOTAL]
    const float* __restrict__ w,    // [COUT, CIN, TOTAL]
    const float* __restrict__ d1,   // [KG, TOTAL]
    const float* __restrict__ d2,   // [KG, TOTAL]
    const float* __restrict__ ca1,  // [NM, KG]
    const float* __restrict__ cg1,  // [NM, KG]
    const float* __restrict__ ca2,  // [NM, KG]
    const float* __restrict__ cg2,  // [NM, KG]
    float* __restrict__ out)        // [B, COUT]
{
    __shared__ __align__(16) float Zs[QPP * 2 * ZPERQ];  // 50688 B: y*d products, zero-padded
    __shared__ __align__(16) float ySm[288];
    __shared__ float redw[QPP];

    const int tid  = threadIdx.x;
    const int lane = tid & 63;
    const int wid  = tid >> 6;
    const int bo   = blockIdx.x;
    const int b    = bo >> 5;
    const int o    = bo & 31;

    // ---- y[i] = sum_c x[b,c,i]*w[o,c,i]
    if (tid < TOTAL) {
        const float* xp = x + b * CIN * TOTAL + tid;
        const float* wp = w + o * CIN * TOTAL + tid;
        float acc = 0.f;
        #pragma unroll
        for (int c = 0; c < CIN; ++c)
            acc = fmaf(xp[c * TOTAL], wp[c * TOTAL], acc);
        ySm[tid] = acc;
    }

    // ---- q-invariant fragment preloads (global scattered, VMEM pipe; f32->f16)
    // MFMA 16x16x16f16 layouts: A[m][k]: lane holds (m=lane&15, k=4*(lane>>4)+i)
    //                           B[k][n]: lane holds (k=4*(lane>>4)+i, n=lane&15)
    //                           D[m][n]: lane holds (m=4*(lane>>4)+j, n=lane&15)
    const int fr = lane & 15;   // row-ish index
    const int g  = lane >> 4;   // k-group
    v4h G1f[2], G2f[2], A1f[2], A2f[2];
    #pragma unroll
    for (int t = 0; t < 2; ++t) {
        #pragma unroll
        for (int i = 0; i < 4; ++i) {
            const int k = 4 * g + i;          // n (for G) or m (for ca)
            const int c = fr + 16 * t;        // r (for G) or p (for ca)
            const bool v = (k < NM);
            G1f[t][i] = (_Float16)(v ? cg1[k * KG + c] : 0.f);
            G2f[t][i] = (_Float16)(v ? cg2[k * KG + c] : 0.f);
            A1f[t][i] = (_Float16)(v ? ca1[k * KG + c] : 0.f);
            A2f[t][i] = (_Float16)(v ? ca2[k * KG + c] : 0.f);
        }
    }

    __syncthreads();   // ySm ready

    float lmax = -INFINITY;
    const v4f zero4 = {0.f, 0.f, 0.f, 0.f};

    for (int ph = 0; ph < NPH; ++ph) {
        // ---- Z build: task e = ((qw*6 + l)*11 + m)*3 + g3; thread writes one
        // 16B-aligned group of 4 n-slots for both channels (b128 writes).
        for (int e = tid; e < QPP * 6 * NM * 3; e += 512) {
            const int g3 = e % 3;
            int rest = e / 3;
            const int m = rest % NM;  rest /= NM;
            const int l = rest % 6;
            const int qw = rest / 6;
            const int q = ph * QPP + qw;
            v4f z1 = zero4, z2 = zero4;
            const int am = (m < 5) ? 5 - m : m - 5;
            if (am <= l) {
                const int t2l = 2 * l + 1;
                const int base = l * (4 * l * l - 1) / 3 + t2l * (l + m - 5) + (l - 5); // i = base + n
                #pragma unroll
                for (int j = 0; j < 4; ++j) {
                    const int n = 4 * g3 + j;
                    const int an = (n < 5) ? 5 - n : n - 5;
                    if (n < NM && an <= l) {
                        const int i = base + n;
                        const float yv = ySm[i];
                        z1[j] = yv * d1[q * TOTAL + i];
                        z2[j] = yv * d2[q * TOTAL + i];
                    }
                }
            }
            const int zb = (qw * 2) * ZPERQ + (l * NM + m) * ZROW + 4 * g3;
            *(v4f*)&Zs[zb]         = z1;
            *(v4f*)&Zs[zb + ZPERQ] = z2;
        }
        __syncthreads();

        // ---- Stage A: S1[m][n] = sum_l Z1[l][m][n] (wave wid owns q = ph*8+wid)
        v4f s1 = zero4, s2 = zero4;
        if (fr < NM && g < 3) {
            const int zq = (wid * 2) * ZPERQ;
            #pragma unroll
            for (int l = 0; l < 6; ++l) {
                const int off = (l * NM + fr) * ZROW + 4 * g;
                s1 += *(const v4f*)&Zs[zq + off];
                s2 += *(const v4f*)&Zs[zq + ZPERQ + off];
            }
        }
        v4h a1, a2;
        #pragma unroll
        for (int i = 0; i < 4; ++i) { a1[i] = (_Float16)s1[i]; a2[i] = (_Float16)s2[i]; }

        // ---- GEMM-B: T = S * G  (K = n-dim, padded to 16)
        v4f t1a = __builtin_amdgcn_mfma_f32_16x16x16f16(a1, G1f[0], zero4, 0, 0, 0);
        v4f t1b = __builtin_amdgcn_mfma_f32_16x16x16f16(a1, G1f[1], zero4, 0, 0, 0);
        v4f t2a = __builtin_amdgcn_mfma_f32_16x16x16f16(a2, G2f[0], zero4, 0, 0, 0);
        v4f t2b = __builtin_amdgcn_mfma_f32_16x16x16f16(a2, G2f[1], zero4, 0, 0, 0);
        // D-frag (m-rows 4g+j, col fr) == B-frag (k 4g+i, col fr): chain in regs.
        v4h b1a, b1b, b2a, b2b;
        #pragma unroll
        for (int i = 0; i < 4; ++i) {
            b1a[i] = (_Float16)t1a[i]; b1b[i] = (_Float16)t1b[i];
            b2a[i] = (_Float16)t2a[i]; b2b[i] = (_Float16)t2b[i];
        }

        // ---- GEMM-C: resp = ca1^T * T1 + ca2^T * T2  (K = m-dim, padded to 16)
        #pragma unroll
        for (int pt = 0; pt < 2; ++pt) {
            v4f acc0 = __builtin_amdgcn_mfma_f32_16x16x16f16(A2f[pt], b2a, zero4, 0, 0, 0);
            acc0     = __builtin_amdgcn_mfma_f32_16x16x16f16(A1f[pt], b1a, acc0, 0, 0, 0);
            v4f acc1 = __builtin_amdgcn_mfma_f32_16x16x16f16(A2f[pt], b2b, zero4, 0, 0, 0);
            acc1     = __builtin_amdgcn_mfma_f32_16x16x16f16(A1f[pt], b1b, acc1, 0, 0, 0);
            #pragma unroll
            for (int j = 0; j < 4; ++j) {
                lmax = fmaxf(lmax, acc0[j]);
                lmax = fmaxf(lmax, acc1[j]);
            }
        }
        __syncthreads();   // all waves done reading Zs before next phase overwrites
    }

    // ---- block max reduction
    #pragma unroll
    for (int off = 32; off > 0; off >>= 1)
        lmax = fmaxf(lmax, __shfl_xor(lmax, off, 64));
    if (lane == 0) redw[wid] = lmax;
    __syncthreads();
    if (tid == 0) {
        float v = redw[0];
        #pragma unroll
        for (int i = 1; i < QPP; ++i) v = fmaxf(v, redw[i]);
        out[bo] = v;
    }
}

extern "C" void kernel_launch(void* const* d_in, const int* in_sizes, int n_in,
                              void* d_out, int out_size, void* d_ws, size_t ws_size,
                              hipStream_t stream) {
    const float* x   = (const float*)d_in[0];
    const float* w   = (const float*)d_in[1];
    const float* d1  = (const float*)d_in[2];
    const float* d2  = (const float*)d_in[3];
    const float* ca1 = (const float*)d_in[4];
    const float* cg1 = (const float*)d_in[5];
    const float* ca2 = (const float*)d_in[6];
    const float* cg2 = (const float*)d_in[7];

    so3_mfma_kernel<<<BB * COUT, 512, 0, stream>>>(
        x, w, d1, d2, ca1, cg1, ca2, cg2, (float*)d_out);
}

// Round 4
// 18.129 us; speedup vs baseline: 1.2227x; 1.2227x over previous
//
#include <hip/hip_runtime.h>

#define TOTAL 286
#define KG 32      // grid points per Euler angle
#define NM 11      // 2L-1
#define CIN 16
#define COUT 32
#define BB 8
#define DROW 12                  // padded n-columns (16B-aligned v4 slots)
#define DPQ (6 * 16 * DROW)      // 1152 floats per (q, channel)

typedef float    v4f __attribute__((ext_vector_type(4)));
typedef _Float16 v4h __attribute__((ext_vector_type(4)));

// ---- prep: zero-padded aligned copies of d1/d2 -> ws as Dp[q][l][m][12]
__global__ __launch_bounds__(256) void so3_prep(
    const float* __restrict__ d1, const float* __restrict__ d2,
    float* __restrict__ D1p, float* __restrict__ D2p)
{
    const int e = blockIdx.x * 256 + threadIdx.x;   // KG*6*16*3 = 9216 tasks
    if (e >= KG * 6 * 16 * 3) return;
    const int g = e % 3;
    int rest = e / 3;
    const int m = rest & 15; rest >>= 4;
    const int l = rest % 6;
    const int q = rest / 6;
    v4f z1 = {0.f, 0.f, 0.f, 0.f}, z2 = z1;
    const int mp = m - 5;
    if (mp >= -l && mp <= l) {
        const int base = l * (4 * l * l - 1) / 3 + (2 * l + 1) * (l + mp) + l - 5; // + n
        #pragma unroll
        for (int j = 0; j < 4; ++j) {
            const int n = 4 * g + j, np = n - 5;
            if (np >= -l && np <= l) {
                z1[j] = d1[q * TOTAL + base + n];
                z2[j] = d2[q * TOTAL + base + n];
            }
        }
    }
    const int o = ((q * 6 + l) * 16 + m) * DROW + 4 * g;
    *(v4f*)&D1p[o] = z1;
    *(v4f*)&D2p[o] = z2;
}

// ---- main: one block per (b,o), 1024 threads (16 waves), wave owns q and q+16.
// No barriers in the q-loop: stage A is uniform aligned loads from Yp(LDS)/Dp(L2),
// stages B/C are the register-chained 16x16x16 f16 MFMAs (verified round 3).
__global__ __launch_bounds__(1024) void so3_main(
    const float* __restrict__ x,    // [B, CIN, TOTAL]
    const float* __restrict__ w,    // [COUT, CIN, TOTAL]
    const float* __restrict__ ca1,  // [NM, KG]
    const float* __restrict__ cg1,  // [NM, KG]
    const float* __restrict__ ca2,  // [NM, KG]
    const float* __restrict__ cg2,  // [NM, KG]
    const float* __restrict__ D1p,  // [KG][6][16][12]
    const float* __restrict__ D2p,
    float* __restrict__ out)        // [B, COUT]
{
    __shared__ float ySm[288];
    __shared__ __align__(16) float Yp[DPQ];   // y padded like Dp (q-independent)
    __shared__ float redw[16];

    const int tid  = threadIdx.x;
    const int lane = tid & 63;
    const int wid  = tid >> 6;          // 0..15
    const int bo   = blockIdx.x;
    const int b    = bo >> 5;
    const int o    = bo & 31;

    // y[i] = sum_c x[b,c,i] * w[o,c,i]   (coalesced over i per c)
    if (tid < TOTAL) {
        const float* xp = x + b * CIN * TOTAL + tid;
        const float* wp = w + o * CIN * TOTAL + tid;
        float acc = 0.f;
        #pragma unroll
        for (int c = 0; c < CIN; ++c)
            acc = fmaf(xp[c * TOTAL], wp[c * TOTAL], acc);
        ySm[tid] = acc;
    }

    // q-invariant MFMA fragments (layouts verified in round 3):
    // A[m][k]: lane=(m=lane&15, k=4*(lane>>4)+i); B[k][n]: (k=4g+i, n=fr);
    // D[m][n]: (m=4g+j, n=fr) == B-frag -> register chaining.
    const int fr = lane & 15;
    const int g  = lane >> 4;
    v4h G1f[2], G2f[2], A1f[2], A2f[2];
    #pragma unroll
    for (int t = 0; t < 2; ++t) {
        #pragma unroll
        for (int i = 0; i < 4; ++i) {
            const int k = 4 * g + i;
            const int c = fr + 16 * t;
            const bool v = (k < NM);
            G1f[t][i] = (_Float16)(v ? cg1[k * KG + c] : 0.f);
            G2f[t][i] = (_Float16)(v ? cg2[k * KG + c] : 0.f);
            A1f[t][i] = (_Float16)(v ? ca1[k * KG + c] : 0.f);
            A2f[t][i] = (_Float16)(v ? ca2[k * KG + c] : 0.f);
        }
    }
    __syncthreads();   // ySm ready

    // Pad y into Yp[l][m][12] (zeros where invalid). 288 tasks.
    if (tid < 6 * 16 * 3) {
        const int gg = tid % 3;
        int rest = tid / 3;
        const int m = rest & 15;
        const int l = rest >> 4;
        v4f z = {0.f, 0.f, 0.f, 0.f};
        const int mp = m - 5;
        if (mp >= -l && mp <= l) {
            const int base = l * (4 * l * l - 1) / 3 + (2 * l + 1) * (l + mp) + l - 5;
            #pragma unroll
            for (int j = 0; j < 4; ++j) {
                const int n = 4 * gg + j, np = n - 5;
                if (np >= -l && np <= l) z[j] = ySm[base + n];
            }
        }
        *(v4f*)&Yp[(l * 16 + m) * DROW + 4 * gg] = z;
    }
    __syncthreads();   // Yp ready — no more barriers until the final reduce

    float lmax = -INFINITY;
    const v4f zero4 = {0.f, 0.f, 0.f, 0.f};

    #pragma unroll
    for (int qi = 0; qi < 2; ++qi) {
        const int q = wid + 16 * qi;

        // ---- Stage A: S[fr][4g..4g+3] = sum_l Yp * Dp (uniform, aligned, padded)
        v4f s1 = zero4, s2 = zero4;
        if (g < 3) {
            const float* D1q = D1p + q * DPQ;
            const float* D2q = D2p + q * DPQ;
            #pragma unroll
            for (int l = 0; l < 6; ++l) {
                const int off = (l * 16 + fr) * DROW + 4 * g;
                const v4f yv = *(const v4f*)&Yp[off];
                s1 += yv * *(const v4f*)&D1q[off];
                s2 += yv * *(const v4f*)&D2q[off];
            }
        }
        v4h a1, a2;
        #pragma unroll
        for (int i = 0; i < 4; ++i) { a1[i] = (_Float16)s1[i]; a2[i] = (_Float16)s2[i]; }

        // ---- GEMM-B: T = S * G (K = n, padded to 16)
        v4f t1a = __builtin_amdgcn_mfma_f32_16x16x16f16(a1, G1f[0], zero4, 0, 0, 0);
        v4f t1b = __builtin_amdgcn_mfma_f32_16x16x16f16(a1, G1f[1], zero4, 0, 0, 0);
        v4f t2a = __builtin_amdgcn_mfma_f32_16x16x16f16(a2, G2f[0], zero4, 0, 0, 0);
        v4f t2b = __builtin_amdgcn_mfma_f32_16x16x16f16(a2, G2f[1], zero4, 0, 0, 0);
        v4h b1a, b1b, b2a, b2b;
        #pragma unroll
        for (int i = 0; i < 4; ++i) {
            b1a[i] = (_Float16)t1a[i]; b1b[i] = (_Float16)t1b[i];
            b2a[i] = (_Float16)t2a[i]; b2b[i] = (_Float16)t2b[i];
        }

        // ---- GEMM-C: resp = ca1^T*T1 + ca2^T*T2 (K = m, padded to 16)
        #pragma unroll
        for (int pt = 0; pt < 2; ++pt) {
            v4f acc0 = __builtin_amdgcn_mfma_f32_16x16x16f16(A2f[pt], b2a, zero4, 0, 0, 0);
            acc0     = __builtin_amdgcn_mfma_f32_16x16x16f16(A1f[pt], b1a, acc0, 0, 0, 0);
            v4f acc1 = __builtin_amdgcn_mfma_f32_16x16x16f16(A2f[pt], b2b, zero4, 0, 0, 0);
            acc1     = __builtin_amdgcn_mfma_f32_16x16x16f16(A1f[pt], b1b, acc1, 0, 0, 0);
            #pragma unroll
            for (int j = 0; j < 4; ++j) {
                lmax = fmaxf(lmax, acc0[j]);
                lmax = fmaxf(lmax, acc1[j]);
            }
        }
    }

    // ---- reduction: wave shuffle, then across 16 waves
    #pragma unroll
    for (int off = 32; off > 0; off >>= 1)
        lmax = fmaxf(lmax, __shfl_xor(lmax, off, 64));
    if (lane == 0) redw[wid] = lmax;
    __syncthreads();
    if (tid == 0) {
        float v = redw[0];
        #pragma unroll
        for (int i = 1; i < 16; ++i) v = fmaxf(v, redw[i]);
        out[bo] = v;
    }
}

extern "C" void kernel_launch(void* const* d_in, const int* in_sizes, int n_in,
                              void* d_out, int out_size, void* d_ws, size_t ws_size,
                              hipStream_t stream) {
    const float* x   = (const float*)d_in[0];
    const float* w   = (const float*)d_in[1];
    const float* d1  = (const float*)d_in[2];
    const float* d2  = (const float*)d_in[3];
    const float* ca1 = (const float*)d_in[4];
    const float* cg1 = (const float*)d_in[5];
    const float* ca2 = (const float*)d_in[6];
    const float* cg2 = (const float*)d_in[7];

    float* D1p = (float*)d_ws;                 // KG*DPQ = 36864 floats
    float* D2p = D1p + KG * DPQ;               // + 36864 floats (294912 B total)

    so3_prep<<<(KG * 6 * 16 * 3 + 255) / 256, 256, 0, stream>>>(d1, d2, D1p, D2p);
    so3_main<<<BB * COUT, 1024, 0, stream>>>(x, w, ca1, cg1, ca2, cg2, D1p, D2p, (float*)d_out);
}